// Round 1
// baseline (11107.961 us; speedup 1.0000x reference)
//
#include <hip/hip_runtime.h>
#include <cstdint>

typedef __attribute__((ext_vector_type(8))) short short8;   // 8 bf16 in 4 VGPRs
typedef __attribute__((ext_vector_type(4))) float floatx4;

typedef unsigned short u16;
typedef unsigned int u32;

__device__ __forceinline__ u16 f2bf(float x) {
    u32 u = __builtin_bit_cast(u32, x);
    u32 r = (u + 0x7fffu + ((u >> 16) & 1u)) >> 16;
    return (u16)r;
}
__device__ __forceinline__ float bf2f(u16 u) {
    return __builtin_bit_cast(float, (u32)u << 16);
}

__device__ __forceinline__ void gload_lds16(const void* g, void* l) {
    __builtin_amdgcn_global_load_lds(
        (const __attribute__((address_space(1))) void*)g,
        (__attribute__((address_space(3))) void*)l, 16, 0, 0);
}

// ---------------- f32 -> bf16 convert (vectorized, 8 elems/thread) ----------
__global__ __launch_bounds__(256) void cvt_f32_bf16(const float* __restrict__ src,
                                                    u16* __restrict__ dst, long n) {
    long i = ((long)blockIdx.x * 256 + threadIdx.x) * 8;
    if (i >= n) return;
    float4 a = *(const float4*)(src + i);
    float4 b = *(const float4*)(src + i + 4);
    short8 o;
    o[0] = (short)f2bf(a.x); o[1] = (short)f2bf(a.y);
    o[2] = (short)f2bf(a.z); o[3] = (short)f2bf(a.w);
    o[4] = (short)f2bf(b.x); o[5] = (short)f2bf(b.y);
    o[6] = (short)f2bf(b.z); o[7] = (short)f2bf(b.w);
    *(short8*)(dst + i) = o;
}

// ---------------- h0 init (parity 0) ----------------------------------------
__global__ __launch_bounds__(256) void h_init(const float* __restrict__ h0,
                                              float* __restrict__ H32,
                                              u16* __restrict__ H16, int layer) {
    int idx = blockIdx.x * 256 + threadIdx.x;   // 0..131071  (= 2*64*1024)
    int d = idx >> 16;
    int rest = idx & 65535;
    float v = h0[(long)(2 * layer + d) * 65536 + rest];
    H32[d * 65536 + rest] = v;         // parity 0
    H16[d * 65536 + rest] = f2bf(v);
}

// ---------------- input-projection GEMM: C[m][n] = sum_k A[m][k]*B[n][k] ----
// A: [16384][2048] bf16, B: [6144][2048] bf16 (row = gate col), C: [16384][6144] bf16
// 128x128 tile, BK=64, 4 waves (2x2), global_load_lds staging.
__global__ __launch_bounds__(256) void gemm_bt_bf16(const u16* __restrict__ A,
                                                    const u16* __restrict__ B,
                                                    u16* __restrict__ C) {
    __shared__ u16 As[128 * 64];
    __shared__ u16 Bs[128 * 64];
    const int tid = threadIdx.x;
    const int w = tid >> 6, l = tid & 63;
    const int m0 = blockIdx.y * 128;
    const int n0 = blockIdx.x * 128;
    const int wr = w >> 1, wc = w & 1;

    floatx4 acc[4][4] = {};

    const int lr = tid >> 3;   // 0..31
    const int ch = tid & 7;    // 16B chunk 0..7 within a 128B row
    const u16* gA = A + (long)(m0 + lr) * 2048 + ch * 8;
    const u16* gB = B + (long)(n0 + lr) * 2048 + ch * 8;

    for (int kt = 0; kt < 32; ++kt) {
        const long ko = kt * 64;
#pragma unroll
        for (int c = 0; c < 4; ++c)
            gload_lds16(gA + (long)c * 65536 + ko, &As[c * 2048 + tid * 8]);
#pragma unroll
        for (int c = 0; c < 4; ++c)
            gload_lds16(gB + (long)c * 65536 + ko, &Bs[c * 2048 + tid * 8]);
        __syncthreads();
#pragma unroll
        for (int ks = 0; ks < 2; ++ks) {
            short8 af[4], bfr[4];
#pragma unroll
            for (int mt = 0; mt < 4; ++mt)
                af[mt] = *(const short8*)&As[(wr * 64 + mt * 16 + (l & 15)) * 64 + ks * 32 + (l >> 4) * 8];
#pragma unroll
            for (int nt = 0; nt < 4; ++nt)
                bfr[nt] = *(const short8*)&Bs[(wc * 64 + nt * 16 + (l & 15)) * 64 + ks * 32 + (l >> 4) * 8];
#pragma unroll
            for (int mt = 0; mt < 4; ++mt)
#pragma unroll
                for (int nt = 0; nt < 4; ++nt)
                    acc[mt][nt] = __builtin_amdgcn_mfma_f32_16x16x32_bf16(af[mt], bfr[nt], acc[mt][nt], 0, 0, 0);
        }
        __syncthreads();
    }
    // epilogue: C/D layout col=l&15, row=(l>>4)*4+i
#pragma unroll
    for (int mt = 0; mt < 4; ++mt)
#pragma unroll
        for (int nt = 0; nt < 4; ++nt) {
            int col = n0 + wc * 64 + nt * 16 + (l & 15);
#pragma unroll
            for (int i = 0; i < 4; ++i) {
                int row = m0 + wr * 64 + mt * 16 + (l >> 4) * 4 + i;
                C[(long)row * 6144 + col] = f2bf(acc[mt][nt][i]);
            }
        }
}

// ---------------- fused GRU recurrent step ----------------------------------
// grid = 128 blocks: dir = bid>>6 (0 fwd, 1 bwd), 16 h-cols per block.
// 4 waves, K-split 4-way (wave w owns K slice [w*256, w*256+256)), LDS reduce.
__global__ __launch_bounds__(256) void gru_step(const u16* __restrict__ WHH,  // [6144][1024]
                                                const u16* __restrict__ GI,   // [16384][6144]
                                                const float* __restrict__ bih, // [2][3072]
                                                const float* __restrict__ bhh,
                                                float* __restrict__ H32,      // [2][2][64][1024]
                                                u16* __restrict__ H16,
                                                u16* __restrict__ Ybf,        // layer<2 out (or null)
                                                float* __restrict__ Yf32,     // layer==2 out (or null)
                                                int s) {
    __shared__ float P[4][4][16][49];   // [k-wave][m-tile][row][col(48 padded)]
    const int tid = threadIdx.x;
    const int w = tid >> 6, l = tid & 63;
    const int dir = blockIdx.x >> 6;
    const int j0 = (blockIdx.x & 63) << 4;
    const int parity = s & 1;
    const int t_eff = dir ? (255 - s) : s;

    const u16* hbase = H16 + parity * 131072 + dir * 65536;        // [64][1024]
    const u16* wbase = WHH + (long)dir * 3072 * 1024;

    floatx4 acc[4][3] = {};
    const int lrow = l & 15;
    const int lk8 = (l >> 4) * 8;

#pragma unroll 2
    for (int kk = 0; kk < 8; ++kk) {
        int k = (w * 8 + kk) * 32 + lk8;
        short8 af[4], bfr[3];
#pragma unroll
        for (int mt = 0; mt < 4; ++mt)
            af[mt] = *(const short8*)&hbase[(mt * 16 + lrow) * 1024 + k];
#pragma unroll
        for (int nt = 0; nt < 3; ++nt)
            bfr[nt] = *(const short8*)&wbase[(long)(nt * 1024 + j0 + lrow) * 1024 + k];
#pragma unroll
        for (int mt = 0; mt < 4; ++mt)
#pragma unroll
            for (int nt = 0; nt < 3; ++nt)
                acc[mt][nt] = __builtin_amdgcn_mfma_f32_16x16x32_bf16(af[mt], bfr[nt], acc[mt][nt], 0, 0, 0);
    }
    // write K-partials
#pragma unroll
    for (int mt = 0; mt < 4; ++mt)
#pragma unroll
        for (int nt = 0; nt < 3; ++nt)
#pragma unroll
            for (int i = 0; i < 4; ++i)
                P[w][mt][(l >> 4) * 4 + i][nt * 16 + lrow] = acc[mt][nt][i];
    __syncthreads();

    // reduce + gates: wave w owns m-tile w (batch rows w*16..w*16+15)
    const int j = lrow;
    const int jg = j0 + j;
    const float bihR = bih[dir * 3072 + jg];
    const float bihZ = bih[dir * 3072 + 1024 + jg];
    const float bihN = bih[dir * 3072 + 2048 + jg];
    const float bhhR = bhh[dir * 3072 + jg];
    const float bhhZ = bhh[dir * 3072 + 1024 + jg];
    const float bhhN = bhh[dir * 3072 + 2048 + jg];

#pragma unroll
    for (int i = 0; i < 4; ++i) {
        int r_loc = (l >> 4) * 4 + i;
        int b = w * 16 + r_loc;
        float ghR = 0.f, ghZ = 0.f, ghN = 0.f;
#pragma unroll
        for (int wp = 0; wp < 4; ++wp) {
            ghR += P[wp][w][r_loc][j];
            ghZ += P[wp][w][r_loc][16 + j];
            ghN += P[wp][w][r_loc][32 + j];
        }
        long girow = (long)(t_eff * 64 + b) * 6144 + dir * 3072 + jg;
        float giR = bf2f(GI[girow]);
        float giZ = bf2f(GI[girow + 1024]);
        float giN = bf2f(GI[girow + 2048]);
        float xr = giR + bihR + ghR + bhhR;
        float xz = giZ + bihZ + ghZ + bhhZ;
        float rg = 1.f / (1.f + __expf(-xr));
        float zg = 1.f / (1.f + __expf(-xz));
        float xn = giN + bihN + rg * (ghN + bhhN);
        xn = fminf(fmaxf(xn, -20.f), 20.f);
        float e2 = __expf(-2.f * xn);
        float ng = (1.f - e2) / (1.f + e2);
        int hidx = dir * 65536 + b * 1024 + jg;
        float hold = H32[parity * 131072 + hidx];
        float hnew = (1.f - zg) * ng + zg * hold;
        H32[(parity ^ 1) * 131072 + hidx] = hnew;
        H16[(parity ^ 1) * 131072 + hidx] = f2bf(hnew);
        long orow = (long)(t_eff * 64 + b) * 2048 + dir * 1024 + jg;
        if (Yf32) Yf32[orow] = hnew;
        else      Ybf[orow] = f2bf(hnew);
    }
}

// ---------------- launch ------------------------------------------------------
extern "C" void kernel_launch(void* const* d_in, const int* in_sizes, int n_in,
                              void* d_out, int out_size, void* d_ws, size_t ws_size,
                              hipStream_t stream) {
    const float* x    = (const float*)d_in[0];
    const float* h0   = (const float*)d_in[1];
    const float* w_ih = (const float*)d_in[2];   // [3][2][3072][2048]
    const float* w_hh = (const float*)d_in[3];   // [3][2][3072][1024]
    const float* b_ih = (const float*)d_in[4];   // [3][2][3072]
    const float* b_hh = (const float*)d_in[5];
    float* out = (float*)d_out;

    char* ws = (char*)d_ws;
    u16*   XB0 = (u16*)(ws);                      //  64 MiB [16384][2048] bf16
    u16*   XB1 = (u16*)(ws + 67108864);           //  64 MiB
    u16*   GI  = (u16*)(ws + 134217728);          // 192 MiB [16384][6144] bf16
    u16*   WIH = (u16*)(ws + 335544320);          //  24 MiB [6144][2048] bf16
    u16*   WHH = (u16*)(ws + 360710144);          //  12 MiB [6144][1024] bf16
    float* H32 = (float*)(ws + 373293056);        //   1 MiB [2][2][64][1024] f32
    u16*   H16 = (u16*)(ws + 374341632);          // 512 KiB same, bf16

    // x -> bf16
    cvt_f32_bf16<<<16384, 256, 0, stream>>>(x, XB0, 33554432L);

    for (int layer = 0; layer < 3; ++layer) {
        const u16* xin = (layer == 1) ? XB1 : XB0;
        u16* yout = (layer == 0) ? XB1 : ((layer == 1) ? XB0 : nullptr);

        cvt_f32_bf16<<<6144, 256, 0, stream>>>(w_ih + (long)layer * 12582912, WIH, 12582912L);
        cvt_f32_bf16<<<3072, 256, 0, stream>>>(w_hh + (long)layer * 6291456, WHH, 6291456L);
        h_init<<<512, 256, 0, stream>>>(h0, H32, H16, layer);

        dim3 g(48, 128);
        gemm_bt_bf16<<<g, 256, 0, stream>>>(xin, WIH, GI);

        const float* bihl = b_ih + (long)layer * 6144;
        const float* bhhl = b_hh + (long)layer * 6144;
        for (int s = 0; s < 256; ++s) {
            gru_step<<<128, 256, 0, stream>>>(WHH, GI, bihl, bhhl, H32, H16,
                                              yout, (layer == 2) ? out : nullptr, s);
        }
    }
}